// Round 11
// baseline (253.960 us; speedup 1.0000x reference)
//
#include <hip/hip_runtime.h>
#include <cstdint>
#include <cstddef>

#define N_ROWS 16384   // B*T
#define KCODES 4096
#define DIM    256

// -------- kernel 1: fused 2-row scan + exact select + gather --------
// One block (4 waves) per TWO rows. Both rows' u (32 KB) + z loaded upfront
// (max outstanding loads), one barrier covers both rows' maxes, ballot-eval
// per row, one barrier, then the 4 waves write {zqA, embA, zqB, embB}.
// Exact numeric path identical to the R10-passing kernel: u-space threshold
// (margin 2.06 >= cos-spread 2 + inversion slop), elementwise-normalized
// fp32 dot, libm logf gumbel, first-index tie-break.
__global__ __launch_bounds__(256, 4) void row2_kernel(
    const float* __restrict__ u, const float* __restrict__ z,
    const float* __restrict__ cb,
    float* __restrict__ zq, float* __restrict__ emb,
    float* __restrict__ idx_out, float* __restrict__ commit_acc)
{
    const int row0 = blockIdx.x * 2;
    const int row1 = row0 + 1;
    const int t = threadIdx.x, lane = t & 63, wave = t >> 6;

    __shared__ float s_max[2][4];
    __shared__ float s_bestv[2][4];
    __shared__ int   s_besti[2][4];

    // ---- phase 1: stream both u rows (32 floats/thread) + both z rows ----
    const float4* ur0 = reinterpret_cast<const float4*>(u + (size_t)row0 * KCODES);
    const float4* ur1 = reinterpret_cast<const float4*>(u + (size_t)row1 * KCODES);
    float4 vA[4], vB[4];
    #pragma unroll
    for (int k = 0; k < 4; ++k) vA[k] = ur0[k * 256 + t];
    #pragma unroll
    for (int k = 0; k < 4; ++k) vB[k] = ur1[k * 256 + t];

    float4 zvA = reinterpret_cast<const float4*>(z + (size_t)row0 * DIM)[lane];
    float4 zvB = reinterpret_cast<const float4*>(z + (size_t)row1 * DIM)[lane];

    float umA = -1.0f, umB = -1.0f;
    #pragma unroll
    for (int k = 0; k < 4; ++k) {
        umA = fmaxf(umA, fmaxf(fmaxf(vA[k].x, vA[k].y), fmaxf(vA[k].z, vA[k].w)));
        umB = fmaxf(umB, fmaxf(fmaxf(vB[k].x, vB[k].y), fmaxf(vB[k].z, vB[k].w)));
    }
    #pragma unroll
    for (int m = 1; m <= 32; m <<= 1) {
        umA = fmaxf(umA, __shfl_xor(umA, m));
        umB = fmaxf(umB, __shfl_xor(umB, m));
    }
    if (lane == 0) { s_max[0][wave] = umA; s_max[1][wave] = umB; }

    // z normalize (both rows, overlaps other waves' max writes)
    float ssA = zvA.x*zvA.x + zvA.y*zvA.y + zvA.z*zvA.z + zvA.w*zvA.w;
    float ssB = zvB.x*zvB.x + zvB.y*zvB.y + zvB.z*zvB.z + zvB.w*zvB.w;
    #pragma unroll
    for (int m = 1; m <= 32; m <<= 1) {
        ssA += __shfl_xor(ssA, m);
        ssB += __shfl_xor(ssB, m);
    }
    const float ziA = 1.0f / fmaxf(sqrtf(ssA), 1e-12f);
    const float ziB = 1.0f / fmaxf(sqrtf(ssB), 1e-12f);
    float4 znA, znB;
    znA.x = zvA.x*ziA; znA.y = zvA.y*ziA; znA.z = zvA.z*ziA; znA.w = zvA.w*ziA;
    znB.x = zvB.x*ziB; znB.y = zvB.y*ziB; znB.z = zvB.z*ziB; znB.w = zvB.w*ziB;

    __syncthreads();
    const float umaxA = fmaxf(fmaxf(s_max[0][0], s_max[0][1]), fmaxf(s_max[0][2], s_max[0][3]));
    const float umaxB = fmaxf(fmaxf(s_max[1][0], s_max[1][1]), fmaxf(s_max[1][2], s_max[1][3]));

    // invert threshold into u-space (g monotone in u)
    auto uthr_of = [](float umax) {
        const float gmax  = -logf(-logf(umax + 1e-10f) + 1e-10f);
        const float y_thr = expf(-(gmax - 2.06f)) - 1e-10f;
        float u_thr = expf(-y_thr) - 1e-10f;
        return u_thr - fabsf(u_thr) * 2e-6f - 1e-12f;   // few-ulp safety shrink
    };
    const float thrA = uthr_of(umaxA);
    const float thrB = uthr_of(umaxB);

    // ---- phase 2: wave-local ballot eval per row ----
    auto evalrow = [&](const float4 (&v)[4], const float4& zn, float u_thr,
                       float& best, int& bi) {
        #pragma unroll
        for (int k = 0; k < 4; ++k) {
            float vv[4] = {v[k].x, v[k].y, v[k].z, v[k].w};
            #pragma unroll
            for (int e = 0; e < 4; ++e) {
                unsigned long long m = __ballot(vv[e] >= u_thr);
                while (m) {
                    int src = __ffsll(m) - 1;
                    m &= m - 1;
                    float uu  = __shfl(vv[e], src);
                    // load was ur[k*256 + wave*64 + lane] -> element col:
                    int   col = k * 1024 + wave * 256 + src * 4 + e;
                    float4 cv = reinterpret_cast<const float4*>(cb + (size_t)col * DIM)[lane];
                    float sc = cv.x*cv.x + cv.y*cv.y + cv.z*cv.z + cv.w*cv.w;
                    #pragma unroll
                    for (int mm = 1; mm <= 32; mm <<= 1) sc += __shfl_xor(sc, mm);
                    float civ = 1.0f / fmaxf(sqrtf(sc), 1e-12f);
                    float d = zn.x*(cv.x*civ) + zn.y*(cv.y*civ) + zn.z*(cv.z*civ) + zn.w*(cv.w*civ);
                    #pragma unroll
                    for (int mm = 1; mm <= 32; mm <<= 1) d += __shfl_xor(d, mm);
                    float y1 = -logf(uu + 1e-10f);
                    float g  = -logf(y1 + 1e-10f);
                    float val = (d - 1.0f) + g;
                    if (val > best || (val == best && col < bi)) { best = val; bi = col; }
                }
            }
        }
    };

    float bestA = -3.0e38f, bestB = -3.0e38f;
    int   biA = 1 << 30,    biB = 1 << 30;
    evalrow(vA, znA, thrA, bestA, biA);
    evalrow(vB, znB, thrB, bestB, biB);
    if (lane == 0) {
        s_bestv[0][wave] = bestA; s_besti[0][wave] = biA;
        s_bestv[1][wave] = bestB; s_besti[1][wave] = biB;
    }
    __syncthreads();

    // ---- phase 3: combine; waves 0/1 -> row A, waves 2/3 -> row B ----
    const int r  = (wave >> 1);                 // 0: row A, 1: row B
    const int rw = (wave & 1);                  // 0: zq+idx+commit, 1: emb
    float best = s_bestv[r][0]; int bi = s_besti[r][0];
    #pragma unroll
    for (int w = 1; w < 4; ++w) {
        float ov = s_bestv[r][w]; int oi = s_besti[r][w];
        if (ov > best || (ov == best && oi < bi)) { best = ov; bi = oi; }
    }
    const int grow = row0 + r;
    const float4 zv = r ? zvB : zvA;
    float4 cw = reinterpret_cast<const float4*>(cb + (size_t)bi * DIM)[lane];
    if (rw == 0) {
        reinterpret_cast<float4*>(zq + (size_t)grow * DIM)[lane] = cw;
        float dx = cw.x - zv.x, dy = cw.y - zv.y, dz = cw.z - zv.z, dw = cw.w - zv.w;
        float s2 = dx*dx + dy*dy + dz*dz + dw*dw;
        #pragma unroll
        for (int m = 1; m <= 32; m <<= 1) s2 += __shfl_xor(s2, m);
        if (lane == 0) {
            idx_out[grow] = (float)bi;
            atomicAdd(commit_acc, s2);
        }
    } else {
        reinterpret_cast<float4*>(emb + (size_t)grow * DIM)[lane] = cw;
    }
}

// -------- kernel 2: scalars (commitment, entropy bonus, perplexity, entropy) --------
__global__ __launch_bounds__(256) void scalars_kernel(
    const float* __restrict__ commit_acc, const float* __restrict__ usage,
    const int* __restrict__ step_ptr, float* __restrict__ out4)
{
    __shared__ float red[256];
    int t = threadIdx.x;

    float us = 0.f;
    for (int i = t; i < KCODES; i += 256) us += usage[i];
    red[t] = us; __syncthreads();
    for (int w = 128; w > 0; w >>= 1) { if (t < w) red[t] += red[t + w]; __syncthreads(); }
    float usage_sum = red[0];
    __syncthreads();

    float e = 0.f;
    for (int i = t; i < KCODES; i += 256) {
        float p = (usage_sum > 0.f) ? usage[i] / (usage_sum + 1e-10f) : (1.0f / KCODES);
        e += p * logf(p + 1e-10f);
    }
    red[t] = e; __syncthreads();
    for (int w = 128; w > 0; w >>= 1) { if (t < w) red[t] += red[t + w]; __syncthreads(); }

    if (t == 0) {
        float entropy = -red[0];
        int step_after = step_ptr[0] + 1;
        float bonus_w = 0.05f * (1.0f - (float)step_after / 20000.0f);
        float eb = (step_after < 20000) ? (-bonus_w * entropy) : 0.0f;
        out4[0] = 0.5f * commit_acc[0] / 4194304.0f;
        out4[1] = eb;
        out4[2] = expf(entropy);
        out4[3] = entropy;
    }
}

extern "C" void kernel_launch(void* const* d_in, const int* in_sizes, int n_in,
                              void* d_out, int out_size, void* d_ws, size_t ws_size,
                              hipStream_t stream)
{
    const float* z     = (const float*)d_in[0];   // [16,1024,256]
    const float* u     = (const float*)d_in[1];   // [16,1024,4096]
    const float* cb    = (const float*)d_in[2];   // [4096,256]
    const float* usage = (const float*)d_in[3];   // [4096]
    const int*   step  = (const int*)d_in[4];     // scalar

    float* out  = (float*)d_out;
    float* zq   = out;                 // 4194304
    float* emb  = out + 4194304;       // 4194304
    float* idxo = out + 8388608;       // 16384
    float* scal = out + 8404992;       // 4

    float* commit_acc = (float*)d_ws;  // single accumulator

    hipMemsetAsync(commit_acc, 0, sizeof(float), stream);
    hipLaunchKernelGGL(row2_kernel, dim3(N_ROWS / 2), dim3(256), 0, stream,
                       u, z, cb, zq, emb, idxo, commit_acc);
    hipLaunchKernelGGL(scalars_kernel, dim3(1), dim3(256), 0, stream,
                       commit_acc, usage, step, scal);
}